// Round 1
// baseline (1723.472 us; speedup 1.0000x reference)
//
#include <hip/hip_runtime.h>
#include <math.h>

typedef float f32x4 __attribute__((ext_vector_type(4)));
typedef short s16x8 __attribute__((ext_vector_type(8)));

__device__ __forceinline__ unsigned short f2bf(float f) {
    unsigned u = __builtin_bit_cast(unsigned, f);
    u += 0x7fffu + ((u >> 16) & 1u);
    return (unsigned short)(u >> 16);
}

// ---------------- weight packing ----------------
// Packs w0,w1,w2,w3,wv (f32, row-major [outF][inF]) into bf16 MFMA B-fragment
// order. Fragment (kt,nt): lane l, elem j holds B[k=32kt+8*(l>>4)+j][n=16nt+(l&15)]
// = W[n][k] (zero-padded for k>=inF).  512 bf16 per fragment.
// layout in ws: w0: off 0   (1 kt x 6 nt = 6 frags, K padded 8->32)
//               w1: off 3072  (3x6=18 frags)   w2: off 12288   w3: off 21504
//               wv: off 30720 (3 kt x 4 nt = 12 frags)
#define PACK_TOT 36864

__global__ __launch_bounds__(256) void pack_weights_k(
    const float* __restrict__ w0, const float* __restrict__ w1,
    const float* __restrict__ w2, const float* __restrict__ w3,
    const float* __restrict__ wv, unsigned short* __restrict__ dst)
{
    int idx = blockIdx.x * 256 + threadIdx.x;
    if (idx >= PACK_TOT) return;
    const float* W; int inF, ntiles, off;
    if (idx < 3072)       { W = w0; inF = 8;  ntiles = 6; off = 0; }
    else if (idx < 12288) { W = w1; inF = 96; ntiles = 6; off = 3072; }
    else if (idx < 21504) { W = w2; inF = 96; ntiles = 6; off = 12288; }
    else if (idx < 30720) { W = w3; inF = 96; ntiles = 6; off = 21504; }
    else                  { W = wv; inF = 96; ntiles = 4; off = 30720; }
    int r  = idx - off;
    int fi = r >> 9;
    int wi = r & 511;
    int l = wi >> 3, j = wi & 7;
    int kt = fi / ntiles, nt = fi - kt * ntiles;
    int n = nt * 16 + (l & 15);
    int k = kt * 32 + ((l >> 4) << 3) + j;
    float v = (k < inF) ? W[n * inF + k] : 0.0f;
    dst[idx] = f2bf(v);
}

// ---------------- fused edge kernel ----------------
// Block = 256 threads = 4 waves; each wave owns 32 edges (2 M-fragments of 16).
// All LDS producer/consumer pairs are wave-private -> no __syncthreads needed.
__global__ __launch_bounds__(256) void edge_kernel(
    const float* __restrict__ r_ij, const int* __restrict__ srcidx,
    const unsigned short* __restrict__ wp,
    const float* __restrict__ b0, const float* __restrict__ b1, const float* __restrict__ b2,
    float* __restrict__ A_a, float* __restrict__ Ov, int E)
{
    __shared__ unsigned short enc_s[128 * 8];
    __shared__ float rv_s[128 * 4];
    __shared__ int src_s[128];
    __shared__ unsigned short h_s[2][128 * 104];   // stride 104 breaks bank-conflict pow2

    const int tid = threadIdx.x;
    const int w  = tid >> 6;
    const int l  = tid & 63;
    const int e0 = blockIdx.x * 128;
    const int lr = l & 15;      // column within a 16-wide fragment
    const int lg = l >> 4;      // lane group 0..3
    const int mbase = w * 32;

    // ---- stage per-edge scalars (lanes 0..31 of each wave handle its own 32 edges)
    if (l < 32) {
        const int ml = mbase + l;
        const int e  = e0 + ml;
        float x = 0.f, y = 0.f, z = 0.f; int s = 0;
        if (e < E) { x = r_ij[3*e]; y = r_ij[3*e+1]; z = r_ij[3*e+2]; s = srcidx[e]; }
        float r = sqrtf(x*x + y*y + z*z);
        float u = r * 4.0f;               // r * 8/R0, R0=2
        s16x8 ev;
        #pragma unroll
        for (int k = 0; k < 8; k++) {
            float t = fmaxf(1.0f - fabsf(u - (float)k), 0.0f);
            ev[k] = (short)f2bf((e < E) ? t : 0.0f);
        }
        *(s16x8*)&enc_s[ml * 8] = ev;
        float nn = 3.5f * r;              // |r_ij * 7/R0|
        float sc = (e < E) ? (3.5f * tanhf(nn) / fmaxf(nn, 1e-12f)) : 0.0f;
        rv_s[ml*4+0] = x * sc; rv_s[ml*4+1] = y * sc; rv_s[ml*4+2] = z * sc;
        src_s[ml] = s;
    }

    // ---- biases into registers (broadcast loads, L1-resident)
    float b0v[6], b1v[6], b2v[6];
    #pragma unroll
    for (int nt = 0; nt < 6; nt++) {
        b0v[nt] = b0[nt*16 + lr];
        b1v[nt] = b1[nt*16 + lr];
        b2v[nt] = b2[nt*16 + lr];
    }

    // ---- layer 0: h0 = enc @ w0.T + b0  (K padded 8->32; lanes>=16 feed zeros)
    {
        s16x8 A0[2];
        #pragma unroll
        for (int mf = 0; mf < 2; mf++) {
            s16x8 a = {0,0,0,0,0,0,0,0};
            if (l < 16) a = *(const s16x8*)&enc_s[(mbase + mf*16 + lr) * 8];
            A0[mf] = a;
        }
        f32x4 acc[2][6];
        #pragma unroll
        for (int nt = 0; nt < 6; nt++) {
            s16x8 B = *(const s16x8*)&wp[nt * 512 + l * 8];
            f32x4 z4 = {0.f,0.f,0.f,0.f};
            acc[0][nt] = __builtin_amdgcn_mfma_f32_16x16x32_bf16(A0[0], B, z4, 0, 0, 0);
            acc[1][nt] = __builtin_amdgcn_mfma_f32_16x16x32_bf16(A0[1], B, z4, 0, 0, 0);
        }
        #pragma unroll
        for (int mf = 0; mf < 2; mf++)
        #pragma unroll
        for (int nt = 0; nt < 6; nt++)
        #pragma unroll
        for (int j = 0; j < 4; j++) {
            float v = acc[mf][nt][j] + b0v[nt];       // no activation after layer 0
            h_s[0][(mbase + mf*16 + lg*4 + j) * 104 + nt*16 + lr] = f2bf(v);
        }
    }

    // ---- layers 1,2: h = leaky(h @ w.T + b)
    #pragma unroll
    for (int li = 0; li < 2; li++) {
        const int pin  = li;          // 0 -> 1 -> 0
        const int pout = li ^ 1;
        const int poff = 3072 + li * 9216;
        s16x8 A[2][3];
        #pragma unroll
        for (int mf = 0; mf < 2; mf++)
        #pragma unroll
        for (int kt = 0; kt < 3; kt++)
            A[mf][kt] = *(const s16x8*)&h_s[pin][(mbase + mf*16 + lr) * 104 + kt*32 + lg*8];
        f32x4 a2[2][6] = {};
        #pragma unroll
        for (int nt = 0; nt < 6; nt++)
        #pragma unroll
        for (int kt = 0; kt < 3; kt++) {
            s16x8 B = *(const s16x8*)&wp[poff + (kt*6 + nt) * 512 + l * 8];
            a2[0][nt] = __builtin_amdgcn_mfma_f32_16x16x32_bf16(A[0][kt], B, a2[0][nt], 0, 0, 0);
            a2[1][nt] = __builtin_amdgcn_mfma_f32_16x16x32_bf16(A[1][kt], B, a2[1][nt], 0, 0, 0);
        }
        #pragma unroll
        for (int mf = 0; mf < 2; mf++)
        #pragma unroll
        for (int nt = 0; nt < 6; nt++)
        #pragma unroll
        for (int j = 0; j < 4; j++) {
            float v = a2[mf][nt][j] + ((li == 0) ? b1v[nt] : b2v[nt]);
            v = (v >= 0.f) ? v : 0.1f * v;
            h_s[pout][(mbase + mf*16 + lg*4 + j) * 104 + nt*16 + lr] = f2bf(v);
        }
    }

    // ---- layer 3: rad = h @ w3.T (no bias, no activation) ----
    f32x4 rad[2][6] = {};
    {
        s16x8 A[2][3];
        #pragma unroll
        for (int mf = 0; mf < 2; mf++)
        #pragma unroll
        for (int kt = 0; kt < 3; kt++)
            A[mf][kt] = *(const s16x8*)&h_s[0][(mbase + mf*16 + lr) * 104 + kt*32 + lg*8];
        #pragma unroll
        for (int nt = 0; nt < 6; nt++)
        #pragma unroll
        for (int kt = 0; kt < 3; kt++) {
            s16x8 B = *(const s16x8*)&wp[21504 + (kt*6 + nt) * 512 + l * 8];
            rad[0][nt] = __builtin_amdgcn_mfma_f32_16x16x32_bf16(A[0][kt], B, rad[0][nt], 0, 0, 0);
            rad[1][nt] = __builtin_amdgcn_mfma_f32_16x16x32_bf16(A[1][kt], B, rad[1][nt], 0, 0, 0);
        }
    }

    // ---- A_a scatter + stash rad (bf16) for the wv GEMM
    #pragma unroll
    for (int mf = 0; mf < 2; mf++)
    #pragma unroll
    for (int nt = 0; nt < 6; nt++)
    #pragma unroll
    for (int j = 0; j < 4; j++) {
        int ml = mbase + mf*16 + lg*4 + j;
        float v = rad[mf][nt][j];
        if (e0 + ml < E)
            unsafeAtomicAdd(&A_a[src_s[ml]*96 + nt*16 + lr], v);
        h_s[1][ml * 104 + nt*16 + lr] = f2bf(v);
    }

    // ---- vrad = rad @ wv.T  (out_v = segsum(vrad x rv): wv pushed before segsum)
    f32x4 av[2][4] = {};
    {
        s16x8 Ar[2][3];
        #pragma unroll
        for (int mf = 0; mf < 2; mf++)
        #pragma unroll
        for (int kt = 0; kt < 3; kt++)
            Ar[mf][kt] = *(const s16x8*)&h_s[1][(mbase + mf*16 + lr) * 104 + kt*32 + lg*8];
        #pragma unroll
        for (int vt = 0; vt < 4; vt++)
        #pragma unroll
        for (int kt = 0; kt < 3; kt++) {
            s16x8 B = *(const s16x8*)&wp[30720 + (kt*4 + vt) * 512 + l * 8];
            av[0][vt] = __builtin_amdgcn_mfma_f32_16x16x32_bf16(Ar[0][kt], B, av[0][vt], 0, 0, 0);
            av[1][vt] = __builtin_amdgcn_mfma_f32_16x16x32_bf16(Ar[1][kt], B, av[1][vt], 0, 0, 0);
        }
    }

    // ---- out_v scatter: out_v[node][v][c] += vrad * rv[c]
    #pragma unroll
    for (int mf = 0; mf < 2; mf++)
    #pragma unroll
    for (int vt = 0; vt < 4; vt++)
    #pragma unroll
    for (int j = 0; j < 4; j++) {
        int ml = mbase + mf*16 + lg*4 + j;
        if (e0 + ml < E) {
            int node = src_s[ml];
            float vv = av[mf][vt][j];
            float rx = rv_s[ml*4+0], ry = rv_s[ml*4+1], rz = rv_s[ml*4+2];
            float* p = Ov + node*192 + (vt*16 + lr)*3;
            unsafeAtomicAdd(p+0, vv*rx);
            unsafeAtomicAdd(p+1, vv*ry);
            unsafeAtomicAdd(p+2, vv*rz);
        }
    }
}

extern "C" void kernel_launch(void* const* d_in, const int* in_sizes, int n_in,
                              void* d_out, int out_size, void* d_ws, size_t ws_size,
                              hipStream_t stream)
{
    const float* r_ij = (const float*)d_in[0];
    const float* w0   = (const float*)d_in[1];
    const float* b0   = (const float*)d_in[2];
    const float* w1   = (const float*)d_in[3];
    const float* b1   = (const float*)d_in[4];
    const float* w2   = (const float*)d_in[5];
    const float* b2   = (const float*)d_in[6];
    const float* w3   = (const float*)d_in[7];
    const float* wv   = (const float*)d_in[8];
    const int*   src  = (const int*)d_in[9];
    const int E = in_sizes[0] / 3;
    const int N = out_size / 288;          // 96 + 64*3 floats per node
    float* A_a = (float*)d_out;
    float* Ov  = A_a + (size_t)N * 96;
    unsigned short* wp = (unsigned short*)d_ws;

    hipMemsetAsync(d_out, 0, (size_t)out_size * sizeof(float), stream);
    pack_weights_k<<<(PACK_TOT + 255) / 256, 256, 0, stream>>>(w0, w1, w2, w3, wv, wp);
    edge_kernel<<<(E + 127) / 128, 256, 0, stream>>>(r_ij, src, wp, b0, b1, b2, A_a, Ov, E);
}

// Round 2
// 533.341 us; speedup vs baseline: 3.2315x; 3.2315x over previous
//
#include <hip/hip_runtime.h>
#include <math.h>

typedef float f32x4 __attribute__((ext_vector_type(4)));
typedef short s16x8 __attribute__((ext_vector_type(8)));

__device__ __forceinline__ unsigned short f2bf(float f) {
    unsigned u = __builtin_bit_cast(unsigned, f);
    u += 0x7fffu + ((u >> 16) & 1u);
    return (unsigned short)(u >> 16);
}
__device__ __forceinline__ float bf2f(unsigned short u) {
    unsigned x = ((unsigned)u) << 16;
    return __builtin_bit_cast(float, x);
}

// ---------------- weight packing ----------------
// Packs w0,w1,w2,w3,wv (f32, row-major [outF][inF]) into bf16 MFMA B-fragment
// order. Fragment (kt,nt): lane l, elem j holds B[k=32kt+8*(l>>4)+j][n=16nt+(l&15)]
// = W[n][k] (zero-padded for k>=inF).  512 bf16 per fragment.
#define PACK_TOT 36864

__global__ __launch_bounds__(256) void pack_weights_k(
    const float* __restrict__ w0, const float* __restrict__ w1,
    const float* __restrict__ w2, const float* __restrict__ w3,
    const float* __restrict__ wv, unsigned short* __restrict__ dst)
{
    int idx = blockIdx.x * 256 + threadIdx.x;
    if (idx >= PACK_TOT) return;
    const float* W; int inF, ntiles, off;
    if (idx < 3072)       { W = w0; inF = 8;  ntiles = 6; off = 0; }
    else if (idx < 12288) { W = w1; inF = 96; ntiles = 6; off = 3072; }
    else if (idx < 21504) { W = w2; inF = 96; ntiles = 6; off = 12288; }
    else if (idx < 30720) { W = w3; inF = 96; ntiles = 6; off = 21504; }
    else                  { W = wv; inF = 96; ntiles = 4; off = 30720; }
    int r  = idx - off;
    int fi = r >> 9;
    int wi = r & 511;
    int l = wi >> 3, j = wi & 7;
    int kt = fi / ntiles, nt = fi - kt * ntiles;
    int n = nt * 16 + (l & 15);
    int k = kt * 32 + ((l >> 4) << 3) + j;
    float v = (k < inF) ? W[n * inF + k] : 0.0f;
    dst[idx] = f2bf(v);
}

// ---------------- CSR build ----------------
__global__ __launch_bounds__(256) void hist_k(const int* __restrict__ src,
                                              int* __restrict__ counts, int E)
{
    int e = blockIdx.x * 256 + threadIdx.x;
    if (e < E) atomicAdd(&counts[src[e]], 1);
}

__global__ __launch_bounds__(1024) void scan_k(const int* __restrict__ counts,
                                               int* __restrict__ rowoff, int N)
{
    __shared__ int sh[1024];
    __shared__ int carry_s;
    int t = threadIdx.x;
    if (t == 0) carry_s = 0;
    __syncthreads();
    int nchunk = (N + 1023) / 1024;
    for (int c = 0; c < nchunk; ++c) {
        int i = c * 1024 + t;
        int v = (i < N) ? counts[i] : 0;
        sh[t] = v;
        __syncthreads();
        int c0 = carry_s;
        #pragma unroll
        for (int off = 1; off < 1024; off <<= 1) {
            int x = (t >= off) ? sh[t - off] : 0;
            __syncthreads();
            sh[t] += x;
            __syncthreads();
        }
        if (i < N) rowoff[i] = c0 + sh[t] - v;   // exclusive prefix
        __syncthreads();
        if (t == 1023) carry_s = c0 + sh[1023];
        __syncthreads();
    }
    if (t == 0) rowoff[N] = carry_s;
}

__global__ __launch_bounds__(256) void scatter_k(const int* __restrict__ src,
                                                 const int* __restrict__ rowoff,
                                                 int* __restrict__ cursor,
                                                 int* __restrict__ order, int E)
{
    int e = blockIdx.x * 256 + threadIdx.x;
    if (e < E) {
        int s = src[e];
        int p = rowoff[s] + atomicAdd(&cursor[s], 1);
        order[p] = e;
    }
}

// ---------------- fused edge kernel (sorted order + segmented reduction) ------
// Block = 256 threads = 4 waves; each wave owns 32 sorted edges (2 M-frags).
// MLP phase is wave-private (no barriers); single barrier before the block-wide
// segmented reduction that replaces per-edge atomics.
__global__ __launch_bounds__(256) void edge_kernel(
    const float* __restrict__ r_ij, const int* __restrict__ srcidx,
    const int* __restrict__ order,
    const unsigned short* __restrict__ wp,
    const float* __restrict__ b0, const float* __restrict__ b1, const float* __restrict__ b2,
    float* __restrict__ A_a, float* __restrict__ Ov, int E)
{
    __shared__ unsigned short enc_s[128 * 8];
    __shared__ float rv_s[128 * 4];
    __shared__ int src_s[128];
    __shared__ unsigned short h_s[2][128 * 104];   // stride 104 breaks pow2 conflicts

    const int tid = threadIdx.x;
    const int w  = tid >> 6;
    const int l  = tid & 63;
    const int e0 = blockIdx.x * 128;
    const int lr = l & 15;
    const int lg = l >> 4;
    const int mbase = w * 32;

    // ---- stage per-edge scalars via sorted gather
    if (l < 32) {
        const int ml = mbase + l;
        const int pos = e0 + ml;
        float x = 0.f, y = 0.f, z = 0.f; int s = -1;
        if (pos < E) {
            int e = order[pos];
            x = r_ij[3*e]; y = r_ij[3*e+1]; z = r_ij[3*e+2];
            s = srcidx[e];
        }
        float r = sqrtf(x*x + y*y + z*z);
        float u = r * 4.0f;               // r * 8/R0, R0=2
        s16x8 ev;
        #pragma unroll
        for (int k = 0; k < 8; k++) {
            float t = fmaxf(1.0f - fabsf(u - (float)k), 0.0f);
            ev[k] = (short)f2bf((s >= 0) ? t : 0.0f);
        }
        *(s16x8*)&enc_s[ml * 8] = ev;
        float nn = 3.5f * r;              // |r_ij * 7/R0|
        float sc = (s >= 0) ? (3.5f * tanhf(nn) / fmaxf(nn, 1e-12f)) : 0.0f;
        rv_s[ml*4+0] = x * sc; rv_s[ml*4+1] = y * sc; rv_s[ml*4+2] = z * sc;
        src_s[ml] = s;
    }

    float b0v[6], b1v[6], b2v[6];
    #pragma unroll
    for (int nt = 0; nt < 6; nt++) {
        b0v[nt] = b0[nt*16 + lr];
        b1v[nt] = b1[nt*16 + lr];
        b2v[nt] = b2[nt*16 + lr];
    }

    // ---- layer 0: h0 = enc @ w0.T + b0  (K padded 8->32)
    {
        s16x8 A0[2];
        #pragma unroll
        for (int mf = 0; mf < 2; mf++) {
            s16x8 a = {0,0,0,0,0,0,0,0};
            if (l < 16) a = *(const s16x8*)&enc_s[(mbase + mf*16 + lr) * 8];
            A0[mf] = a;
        }
        f32x4 acc[2][6];
        #pragma unroll
        for (int nt = 0; nt < 6; nt++) {
            s16x8 B = *(const s16x8*)&wp[nt * 512 + l * 8];
            f32x4 z4 = {0.f,0.f,0.f,0.f};
            acc[0][nt] = __builtin_amdgcn_mfma_f32_16x16x32_bf16(A0[0], B, z4, 0, 0, 0);
            acc[1][nt] = __builtin_amdgcn_mfma_f32_16x16x32_bf16(A0[1], B, z4, 0, 0, 0);
        }
        #pragma unroll
        for (int mf = 0; mf < 2; mf++)
        #pragma unroll
        for (int nt = 0; nt < 6; nt++)
        #pragma unroll
        for (int j = 0; j < 4; j++) {
            float v = acc[mf][nt][j] + b0v[nt];
            h_s[0][(mbase + mf*16 + lg*4 + j) * 104 + nt*16 + lr] = f2bf(v);
        }
    }

    // ---- layers 1,2: h = leaky(h @ w.T + b)
    #pragma unroll
    for (int li = 0; li < 2; li++) {
        const int pin  = li;
        const int pout = li ^ 1;
        const int poff = 3072 + li * 9216;
        s16x8 A[2][3];
        #pragma unroll
        for (int mf = 0; mf < 2; mf++)
        #pragma unroll
        for (int kt = 0; kt < 3; kt++)
            A[mf][kt] = *(const s16x8*)&h_s[pin][(mbase + mf*16 + lr) * 104 + kt*32 + lg*8];
        f32x4 a2[2][6] = {};
        #pragma unroll
        for (int nt = 0; nt < 6; nt++)
        #pragma unroll
        for (int kt = 0; kt < 3; kt++) {
            s16x8 B = *(const s16x8*)&wp[poff + (kt*6 + nt) * 512 + l * 8];
            a2[0][nt] = __builtin_amdgcn_mfma_f32_16x16x32_bf16(A[0][kt], B, a2[0][nt], 0, 0, 0);
            a2[1][nt] = __builtin_amdgcn_mfma_f32_16x16x32_bf16(A[1][kt], B, a2[1][nt], 0, 0, 0);
        }
        #pragma unroll
        for (int mf = 0; mf < 2; mf++)
        #pragma unroll
        for (int nt = 0; nt < 6; nt++)
        #pragma unroll
        for (int j = 0; j < 4; j++) {
            float v = a2[mf][nt][j] + ((li == 0) ? b1v[nt] : b2v[nt]);
            v = (v >= 0.f) ? v : 0.1f * v;
            h_s[pout][(mbase + mf*16 + lg*4 + j) * 104 + nt*16 + lr] = f2bf(v);
        }
    }

    // ---- layer 3: rad = h @ w3.T -> stash bf16 into h_s[1]
    {
        s16x8 A[2][3];
        #pragma unroll
        for (int mf = 0; mf < 2; mf++)
        #pragma unroll
        for (int kt = 0; kt < 3; kt++)
            A[mf][kt] = *(const s16x8*)&h_s[0][(mbase + mf*16 + lr) * 104 + kt*32 + lg*8];
        f32x4 rad[2][6] = {};
        #pragma unroll
        for (int nt = 0; nt < 6; nt++)
        #pragma unroll
        for (int kt = 0; kt < 3; kt++) {
            s16x8 B = *(const s16x8*)&wp[21504 + (kt*6 + nt) * 512 + l * 8];
            rad[0][nt] = __builtin_amdgcn_mfma_f32_16x16x32_bf16(A[0][kt], B, rad[0][nt], 0, 0, 0);
            rad[1][nt] = __builtin_amdgcn_mfma_f32_16x16x32_bf16(A[1][kt], B, rad[1][nt], 0, 0, 0);
        }
        #pragma unroll
        for (int mf = 0; mf < 2; mf++)
        #pragma unroll
        for (int nt = 0; nt < 6; nt++)
        #pragma unroll
        for (int j = 0; j < 4; j++)
            h_s[1][(mbase + mf*16 + lg*4 + j) * 104 + nt*16 + lr] = f2bf(rad[mf][nt][j]);
    }

    // ---- vrad = rad @ wv.T -> stash bf16 into h_s[0] (dead after layer 3)
    {
        s16x8 Ar[2][3];
        #pragma unroll
        for (int mf = 0; mf < 2; mf++)
        #pragma unroll
        for (int kt = 0; kt < 3; kt++)
            Ar[mf][kt] = *(const s16x8*)&h_s[1][(mbase + mf*16 + lr) * 104 + kt*32 + lg*8];
        f32x4 av[2][4] = {};
        #pragma unroll
        for (int vt = 0; vt < 4; vt++)
        #pragma unroll
        for (int kt = 0; kt < 3; kt++) {
            s16x8 B = *(const s16x8*)&wp[30720 + (kt*4 + vt) * 512 + l * 8];
            av[0][vt] = __builtin_amdgcn_mfma_f32_16x16x32_bf16(Ar[0][kt], B, av[0][vt], 0, 0, 0);
            av[1][vt] = __builtin_amdgcn_mfma_f32_16x16x32_bf16(Ar[1][kt], B, av[1][vt], 0, 0, 0);
        }
        #pragma unroll
        for (int mf = 0; mf < 2; mf++)
        #pragma unroll
        for (int vt = 0; vt < 4; vt++)
        #pragma unroll
        for (int j = 0; j < 4; j++)
            h_s[0][(mbase + mf*16 + lg*4 + j) * 104 + vt*16 + lr] = f2bf(av[mf][vt][j]);
    }

    __syncthreads();

    // ---- block-wide segmented reduction over the 128 sorted rows.
    // Feature f<96: A_a[node][f] += rad.  f>=96: q=f-96=(v*3+c): Ov[node][q] += vrad[v]*rv[c].
    // Segment-boundary branch is wave-uniform (all lanes share the row walk).
    for (int f = tid; f < 288; f += 256) {
        if (f < 96) {
            float acc = 0.f; int prev = -2;
            for (int i = 0; i < 128; ++i) {
                int node = src_s[i];
                if (node != prev) {
                    if (prev >= 0) unsafeAtomicAdd(&A_a[prev*96 + f], acc);
                    acc = 0.f; prev = node;
                }
                acc += bf2f(h_s[1][i*104 + f]);
            }
            if (prev >= 0) unsafeAtomicAdd(&A_a[prev*96 + f], acc);
        } else {
            int q = f - 96;
            int vv = q / 3;
            int c  = q - 3*vv;
            float acc = 0.f; int prev = -2;
            for (int i = 0; i < 128; ++i) {
                int node = src_s[i];
                if (node != prev) {
                    if (prev >= 0) unsafeAtomicAdd(&Ov[prev*192 + q], acc);
                    acc = 0.f; prev = node;
                }
                acc += bf2f(h_s[0][i*104 + vv]) * rv_s[i*4 + c];
            }
            if (prev >= 0) unsafeAtomicAdd(&Ov[prev*192 + q], acc);
        }
    }
}

extern "C" void kernel_launch(void* const* d_in, const int* in_sizes, int n_in,
                              void* d_out, int out_size, void* d_ws, size_t ws_size,
                              hipStream_t stream)
{
    const float* r_ij = (const float*)d_in[0];
    const float* w0   = (const float*)d_in[1];
    const float* b0   = (const float*)d_in[2];
    const float* w1   = (const float*)d_in[3];
    const float* b1   = (const float*)d_in[4];
    const float* w2   = (const float*)d_in[5];
    const float* b2   = (const float*)d_in[6];
    const float* w3   = (const float*)d_in[7];
    const float* wv   = (const float*)d_in[8];
    const int*   src  = (const int*)d_in[9];
    const int E = in_sizes[0] / 3;
    const int N = out_size / 288;          // 96 + 64*3 floats per node
    float* A_a = (float*)d_out;
    float* Ov  = A_a + (size_t)N * 96;

    // ws carve-up (all offsets 128B-aligned)
    char* wsb = (char*)d_ws;
    unsigned short* wp = (unsigned short*)wsb;                 // 73728 B
    size_t off = 73728;
    int* counts = (int*)(wsb + off);  off += (size_t)N * 4;    // zeroed
    int* cursor = (int*)(wsb + off);  off += (size_t)N * 4;    // zeroed (adjacent)
    int* rowoff = (int*)(wsb + off);  off += (((size_t)(N+1)*4 + 127) & ~127ull);
    int* order  = (int*)(wsb + off);

    hipMemsetAsync(d_out, 0, (size_t)out_size * sizeof(float), stream);
    hipMemsetAsync(counts, 0, (size_t)N * 8, stream);          // counts + cursor

    pack_weights_k<<<(PACK_TOT + 255) / 256, 256, 0, stream>>>(w0, w1, w2, w3, wv, wp);
    hist_k<<<(E + 255) / 256, 256, 0, stream>>>(src, counts, E);
    scan_k<<<1, 1024, 0, stream>>>(counts, rowoff, N);
    scatter_k<<<(E + 255) / 256, 256, 0, stream>>>(src, rowoff, cursor, order, E);
    edge_kernel<<<(E + 127) / 128, 256, 0, stream>>>(r_ij, src, order, wp,
                                                     b0, b1, b2, A_a, Ov, E);
}

// Round 3
// 298.970 us; speedup vs baseline: 5.7647x; 1.7839x over previous
//
#include <hip/hip_runtime.h>
#include <math.h>

typedef float f32x4 __attribute__((ext_vector_type(4)));
typedef short s16x8 __attribute__((ext_vector_type(8)));

__device__ __forceinline__ unsigned short f2bf(float f) {
    unsigned u = __builtin_bit_cast(unsigned, f);
    u += 0x7fffu + ((u >> 16) & 1u);
    return (unsigned short)(u >> 16);
}

// ---------------- weight packing ----------------
// B-fragment order: frag (kt,nt): lane l, elem j holds W[n=16nt+(l&15)][k=32kt+8*(l>>4)+j]
#define PACK_TOT 36864

__global__ __launch_bounds__(256) void pack_weights_k(
    const float* __restrict__ w0, const float* __restrict__ w1,
    const float* __restrict__ w2, const float* __restrict__ w3,
    const float* __restrict__ wv, unsigned short* __restrict__ dst)
{
    int idx = blockIdx.x * 256 + threadIdx.x;
    if (idx >= PACK_TOT) return;
    const float* W; int inF, ntiles, off;
    if (idx < 3072)       { W = w0; inF = 8;  ntiles = 6; off = 0; }
    else if (idx < 12288) { W = w1; inF = 96; ntiles = 6; off = 3072; }
    else if (idx < 21504) { W = w2; inF = 96; ntiles = 6; off = 12288; }
    else if (idx < 30720) { W = w3; inF = 96; ntiles = 6; off = 21504; }
    else                  { W = wv; inF = 96; ntiles = 4; off = 30720; }
    int r  = idx - off;
    int fi = r >> 9;
    int wi = r & 511;
    int l = wi >> 3, j = wi & 7;
    int kt = fi / ntiles, nt = fi - kt * ntiles;
    int n = nt * 16 + (l & 15);
    int k = kt * 32 + ((l >> 4) << 3) + j;
    float v = (k < inF) ? W[n * inF + k] : 0.0f;
    dst[idx] = f2bf(v);
}

// ---------------- CSR build ----------------
__global__ __launch_bounds__(256) void hist_k(const int* __restrict__ src,
                                              int* __restrict__ counts, int E)
{
    int e = blockIdx.x * 256 + threadIdx.x;
    if (e < E) atomicAdd(&counts[src[e]], 1);
}

// single block, shfl-based exclusive scan; writes cursor = exclusive prefix
__global__ __launch_bounds__(1024) void scan_k(const int* __restrict__ counts,
                                               int* __restrict__ cursor, int N)
{
    __shared__ int wsum_s[16];
    __shared__ int carry_s;
    int t = threadIdx.x, lane = t & 63, wid = t >> 6;
    if (t == 0) carry_s = 0;
    __syncthreads();
    for (int base = 0; base < N; base += 4096) {
        int i0 = base + t * 4;
        int4 v = {0,0,0,0};
        if (i0 + 3 < N) v = *(const int4*)&counts[i0];
        else {
            if (i0   < N) v.x = counts[i0];
            if (i0+1 < N) v.y = counts[i0+1];
            if (i0+2 < N) v.z = counts[i0+2];
        }
        int s01 = v.x + v.y;
        int s = s01 + v.z + v.w;
        int inc = s;
        #pragma unroll
        for (int d = 1; d < 64; d <<= 1) {
            int o = __shfl_up(inc, d, 64);
            if (lane >= d) inc += o;
        }
        if (lane == 63) wsum_s[wid] = inc;
        __syncthreads();
        int c0 = carry_s;
        if (wid == 0) {
            int wv2 = (lane < 16) ? wsum_s[lane] : 0;
            int winc = wv2;
            #pragma unroll
            for (int d = 1; d < 16; d <<= 1) {
                int o = __shfl_up(winc, d, 64);
                if (lane >= d) winc += o;
            }
            if (lane < 16) wsum_s[lane] = winc;
        }
        __syncthreads();
        int wbase = (wid == 0) ? 0 : wsum_s[wid - 1];
        int excl = c0 + wbase + (inc - s);
        if (i0     < N) cursor[i0]     = excl;
        if (i0 + 1 < N) cursor[i0 + 1] = excl + v.x;
        if (i0 + 2 < N) cursor[i0 + 2] = excl + s01;
        if (i0 + 3 < N) cursor[i0 + 3] = excl + s01 + v.z;
        __syncthreads();
        if (t == 0) carry_s = c0 + wsum_s[15];
        __syncthreads();
    }
}

__global__ __launch_bounds__(256) void scatter_k(const int* __restrict__ src,
                                                 int* __restrict__ cursor,
                                                 int* __restrict__ order,
                                                 int* __restrict__ srcs, int E)
{
    int e = blockIdx.x * 256 + threadIdx.x;
    if (e < E) {
        int s = src[e];
        int p = atomicAdd(&cursor[s], 1);
        order[p] = e;
        srcs[p] = s;
    }
}

// ---------------- fused edge kernel ----------------
// 4 waves x 32 sorted edges. MLP in-place in one LDS buffer (wave-private rows).
// Segment reduction done with indicator-matrix MFMAs against fragment-order
// stashes of rad / vrad; one atomic per (segment, feature).
__global__ __launch_bounds__(256, 3) void edge_kernel(
    const float* __restrict__ r_ij,
    const int* __restrict__ order, const int* __restrict__ srcs,
    const unsigned short* __restrict__ wp,
    const float* __restrict__ b0, const float* __restrict__ b1, const float* __restrict__ b2,
    float* __restrict__ A_a, float* __restrict__ Ov, int E)
{
    __shared__ unsigned short h_s[128 * 104];      // MLP buffer; cols 96..103 = enc; frag-stash overlay late
    __shared__ unsigned short vfrag_s[16 * 512];   // vrad B-fragments
    __shared__ unsigned short rvb_s[3 * 128];      // bf16 rv, [c][row]
    __shared__ unsigned char  segid_s[128];
    __shared__ int  segnode_s[128];
    __shared__ int  src_s[128];
    __shared__ int  nseg_s;

    const int tid = threadIdx.x;
    const int w  = tid >> 6;
    const int l  = tid & 63;
    const int e0 = blockIdx.x * 128;
    const int lr = l & 15;
    const int lg = l >> 4;
    const int mbase = w * 32;

    // ---- stage per-edge scalars (sorted order; srcs coalesced, r_ij gathered)
    if (l < 32) {
        const int ml = mbase + l;
        const int pos = e0 + ml;
        float x = 0.f, y = 0.f, z = 0.f; int s = -1;
        if (pos < E) {
            int e = order[pos];
            s = srcs[pos];
            x = r_ij[3*e]; y = r_ij[3*e+1]; z = r_ij[3*e+2];
        }
        float r = sqrtf(x*x + y*y + z*z);
        float u = r * 4.0f;               // r * 8/R0, R0=2
        s16x8 ev;
        #pragma unroll
        for (int k = 0; k < 8; k++) {
            float t = fmaxf(1.0f - fabsf(u - (float)k), 0.0f);
            ev[k] = (short)f2bf((s >= 0) ? t : 0.0f);
        }
        *(s16x8*)&h_s[ml * 104 + 96] = ev;     // enc into pad cols
        float nn = 3.5f * r;
        float sc = (s >= 0) ? (3.5f * tanhf(nn) / fmaxf(nn, 1e-12f)) : 0.0f;
        rvb_s[0*128 + ml] = f2bf(x * sc);
        rvb_s[1*128 + ml] = f2bf(y * sc);
        rvb_s[2*128 + ml] = f2bf(z * sc);
        src_s[ml] = s;
    }
    __syncthreads();   // SYNC#1: src_s/enc visible

    // ---- wave 0: build segid / segnode / nseg (ballot-based prefix)
    if (w == 0) {
        int i = l;
        int sA = src_s[i];
        bool fA = (i == 0) || (sA != src_s[i - 1]);
        unsigned long long mA = __ballot(fA);
        unsigned long long maskA = (~0ull) >> (63 - i);
        int incA = (int)__popcll(mA & maskA);
        segid_s[i] = (unsigned char)(incA - 1);
        if (fA) segnode_s[incA - 1] = sA;
        int totA = (int)__popcll(mA);
        int jrow = 64 + i;
        int sB = src_s[jrow];
        bool fB = (sB != src_s[jrow - 1]);
        unsigned long long mB = __ballot(fB);
        int incB = (int)__popcll(mB & maskA);
        segid_s[jrow] = (unsigned char)(totA + incB - 1);
        if (fB) segnode_s[totA + incB - 1] = sB;
        if (i == 63) nseg_s = totA + (int)__popcll(mB);
    }

    float b0v[6], b1v[6], b2v[6];
    #pragma unroll
    for (int nt = 0; nt < 6; nt++) {
        b0v[nt] = b0[nt*16 + lr];
        b1v[nt] = b1[nt*16 + lr];
        b2v[nt] = b2[nt*16 + lr];
    }

    // ---- layer 0: h = enc @ w0.T + b0 (in place; enc in pad cols)
    {
        s16x8 A0[2];
        #pragma unroll
        for (int mf = 0; mf < 2; mf++) {
            s16x8 a = {0,0,0,0,0,0,0,0};
            if (l < 16) a = *(const s16x8*)&h_s[(mbase + mf*16 + lr) * 104 + 96];
            A0[mf] = a;
        }
        f32x4 acc[2][6];
        #pragma unroll
        for (int nt = 0; nt < 6; nt++) {
            s16x8 B = *(const s16x8*)&wp[nt * 512 + l * 8];
            f32x4 z4 = {0.f,0.f,0.f,0.f};
            acc[0][nt] = __builtin_amdgcn_mfma_f32_16x16x32_bf16(A0[0], B, z4, 0, 0, 0);
            acc[1][nt] = __builtin_amdgcn_mfma_f32_16x16x32_bf16(A0[1], B, z4, 0, 0, 0);
        }
        #pragma unroll
        for (int mf = 0; mf < 2; mf++)
        #pragma unroll
        for (int nt = 0; nt < 6; nt++)
        #pragma unroll
        for (int j = 0; j < 4; j++)
            h_s[(mbase + mf*16 + lg*4 + j) * 104 + nt*16 + lr] = f2bf(acc[mf][nt][j] + b0v[nt]);
    }

    // ---- layers 1,2: in-place leaky(h @ w.T + b)
    #pragma unroll
    for (int li = 0; li < 2; li++) {
        const int poff = 3072 + li * 9216;
        s16x8 A[2][3];
        #pragma unroll
        for (int mf = 0; mf < 2; mf++)
        #pragma unroll
        for (int kt = 0; kt < 3; kt++)
            A[mf][kt] = *(const s16x8*)&h_s[(mbase + mf*16 + lr) * 104 + kt*32 + lg*8];
        f32x4 a2[2][6] = {};
        #pragma unroll
        for (int nt = 0; nt < 6; nt++)
        #pragma unroll
        for (int kt = 0; kt < 3; kt++) {
            s16x8 B = *(const s16x8*)&wp[poff + (kt*6 + nt) * 512 + l * 8];
            a2[0][nt] = __builtin_amdgcn_mfma_f32_16x16x32_bf16(A[0][kt], B, a2[0][nt], 0, 0, 0);
            a2[1][nt] = __builtin_amdgcn_mfma_f32_16x16x32_bf16(A[1][kt], B, a2[1][nt], 0, 0, 0);
        }
        #pragma unroll
        for (int mf = 0; mf < 2; mf++)
        #pragma unroll
        for (int nt = 0; nt < 6; nt++)
        #pragma unroll
        for (int j = 0; j < 4; j++) {
            float v = a2[mf][nt][j] + ((li == 0) ? b1v[nt] : b2v[nt]);
            v = (v >= 0.f) ? v : 0.1f * v;
            h_s[(mbase + mf*16 + lg*4 + j) * 104 + nt*16 + lr] = f2bf(v);
        }
    }

    // ---- layer 3: rad = h @ w3.T (in place) + keep packed copy for frag stash
    uint2 radp[2][6];
    {
        s16x8 A[2][3];
        #pragma unroll
        for (int mf = 0; mf < 2; mf++)
        #pragma unroll
        for (int kt = 0; kt < 3; kt++)
            A[mf][kt] = *(const s16x8*)&h_s[(mbase + mf*16 + lr) * 104 + kt*32 + lg*8];
        f32x4 rad[2][6] = {};
        #pragma unroll
        for (int nt = 0; nt < 6; nt++)
        #pragma unroll
        for (int kt = 0; kt < 3; kt++) {
            s16x8 B = *(const s16x8*)&wp[21504 + (kt*6 + nt) * 512 + l * 8];
            rad[0][nt] = __builtin_amdgcn_mfma_f32_16x16x32_bf16(A[0][kt], B, rad[0][nt], 0, 0, 0);
            rad[1][nt] = __builtin_amdgcn_mfma_f32_16x16x32_bf16(A[1][kt], B, rad[1][nt], 0, 0, 0);
        }
        #pragma unroll
        for (int mf = 0; mf < 2; mf++)
        #pragma unroll
        for (int nt = 0; nt < 6; nt++) {
            unsigned short q0 = f2bf(rad[mf][nt][0]);
            unsigned short q1 = f2bf(rad[mf][nt][1]);
            unsigned short q2 = f2bf(rad[mf][nt][2]);
            unsigned short q3 = f2bf(rad[mf][nt][3]);
            radp[mf][nt].x = (unsigned)q0 | ((unsigned)q1 << 16);
            radp[mf][nt].y = (unsigned)q2 | ((unsigned)q3 << 16);
            h_s[(mbase + mf*16 + lg*4 + 0) * 104 + nt*16 + lr] = q0;
            h_s[(mbase + mf*16 + lg*4 + 1) * 104 + nt*16 + lr] = q1;
            h_s[(mbase + mf*16 + lg*4 + 2) * 104 + nt*16 + lr] = q2;
            h_s[(mbase + mf*16 + lg*4 + 3) * 104 + nt*16 + lr] = q3;
        }
    }

    // ---- vrad = rad @ wv.T  (A-frags from row-major rad; wave-private)
    f32x4 av[2][4] = {};
    {
        s16x8 Ar[2][3];
        #pragma unroll
        for (int mf = 0; mf < 2; mf++)
        #pragma unroll
        for (int kt = 0; kt < 3; kt++)
            Ar[mf][kt] = *(const s16x8*)&h_s[(mbase + mf*16 + lr) * 104 + kt*32 + lg*8];
        #pragma unroll
        for (int vt = 0; vt < 4; vt++)
        #pragma unroll
        for (int kt = 0; kt < 3; kt++) {
            s16x8 B = *(const s16x8*)&wp[30720 + (kt*4 + vt) * 512 + l * 8];
            av[0][vt] = __builtin_amdgcn_mfma_f32_16x16x32_bf16(Ar[0][kt], B, av[0][vt], 0, 0, 0);
            av[1][vt] = __builtin_amdgcn_mfma_f32_16x16x32_bf16(Ar[1][kt], B, av[1][vt], 0, 0, 0);
        }
    }

    __syncthreads();   // SYNC#2: all row-major reads of h done -> overlay allowed

    // ---- rad -> fragment-order stash (overlays h_s[0 .. 24576B))
    // write addr: frag (w*6+nt), lane2 = (2mf+(lg>>1))*16+lr, elem base (lg&1)*4
    #pragma unroll
    for (int mf = 0; mf < 2; mf++)
    #pragma unroll
    for (int nt = 0; nt < 6; nt++)
        *(uint2*)&h_s[(w*6 + nt) * 512 + ((2*mf + (lg>>1))*16 + lr) * 8 + (lg&1)*4] = radp[mf][nt];

    // ---- vrad -> fragment-order stash (wave-private region of vfrag_s)
    #pragma unroll
    for (int mf = 0; mf < 2; mf++)
    #pragma unroll
    for (int vt = 0; vt < 4; vt++) {
        unsigned short q0 = f2bf(av[mf][vt][0]);
        unsigned short q1 = f2bf(av[mf][vt][1]);
        unsigned short q2 = f2bf(av[mf][vt][2]);
        unsigned short q3 = f2bf(av[mf][vt][3]);
        uint2 p; p.x = (unsigned)q0 | ((unsigned)q1 << 16); p.y = (unsigned)q2 | ((unsigned)q3 << 16);
        *(uint2*)&vfrag_s[(w*4 + vt) * 512 + ((2*mf + (lg>>1))*16 + lr) * 8 + (lg&1)*4] = p;
    }

    __syncthreads();   // SYNC#3: stashes + segid visible

    // ---- indicator-MFMA segment reduction
    const int nseg = nseg_s;
    if (w == 0) {
        // A_a[seg][feat] = I @ rad
        for (int st = 0; st * 16 < nseg; ++st) {
            const int target = st * 16 + lr;
            f32x4 acc[6] = {};
            #pragma unroll
            for (int kt = 0; kt < 4; kt++) {
                uint2 sid8 = *(const uint2*)&segid_s[kt*32 + 8*lg];
                s16x8 af;
                #pragma unroll
                for (int j = 0; j < 8; j++) {
                    unsigned word = (j < 4) ? sid8.x : sid8.y;
                    int sid = (word >> (8 * (j & 3))) & 255;
                    af[j] = (short)((sid == target) ? 0x3F80 : 0);
                }
                #pragma unroll
                for (int nt = 0; nt < 6; nt++) {
                    s16x8 B = *(const s16x8*)&h_s[(kt*6 + nt) * 512 + l * 8];
                    acc[nt] = __builtin_amdgcn_mfma_f32_16x16x32_bf16(af, B, acc[nt], 0, 0, 0);
                }
            }
            #pragma unroll
            for (int nt = 0; nt < 6; nt++)
            #pragma unroll
            for (int j = 0; j < 4; j++) {
                int g = st*16 + 4*lg + j;
                if (g < nseg) {
                    int node = segnode_s[g];
                    if (node >= 0)
                        unsafeAtomicAdd(&A_a[node*96 + nt*16 + lr], acc[nt][j]);
                }
            }
        }
    } else {
        // Ov[seg][v] for c = w-1: (I ∘ rv_c) @ vrad
        const int c = w - 1;
        for (int st = 0; st * 16 < nseg; ++st) {
            const int target = st * 16 + lr;
            f32x4 acc[4] = {};
            #pragma unroll
            for (int kt = 0; kt < 4; kt++) {
                uint2 sid8 = *(const uint2*)&segid_s[kt*32 + 8*lg];
                s16x8 rv8 = *(const s16x8*)&rvb_s[c*128 + kt*32 + 8*lg];
                s16x8 af;
                #pragma unroll
                for (int j = 0; j < 8; j++) {
                    unsigned word = (j < 4) ? sid8.x : sid8.y;
                    int sid = (word >> (8 * (j & 3))) & 255;
                    af[j] = (short)((sid == target) ? rv8[j] : (short)0);
                }
                #pragma unroll
                for (int vt = 0; vt < 4; vt++) {
                    s16x8 B = *(const s16x8*)&vfrag_s[(kt*4 + vt) * 512 + l * 8];
                    acc[vt] = __builtin_amdgcn_mfma_f32_16x16x32_bf16(af, B, acc[vt], 0, 0, 0);
                }
            }
            #pragma unroll
            for (int vt = 0; vt < 4; vt++)
            #pragma unroll
            for (int j = 0; j < 4; j++) {
                int g = st*16 + 4*lg + j;
                if (g < nseg) {
                    int node = segnode_s[g];
                    if (node >= 0)
                        unsafeAtomicAdd(&Ov[node*192 + (vt*16 + lr)*3 + c], acc[vt][j]);
                }
            }
        }
    }
}

extern "C" void kernel_launch(void* const* d_in, const int* in_sizes, int n_in,
                              void* d_out, int out_size, void* d_ws, size_t ws_size,
                              hipStream_t stream)
{
    const float* r_ij = (const float*)d_in[0];
    const float* w0   = (const float*)d_in[1];
    const float* b0   = (const float*)d_in[2];
    const float* w1   = (const float*)d_in[3];
    const float* b1   = (const float*)d_in[4];
    const float* w2   = (const float*)d_in[5];
    const float* b2   = (const float*)d_in[6];
    const float* w3   = (const float*)d_in[7];
    const float* wv   = (const float*)d_in[8];
    const int*   src  = (const int*)d_in[9];
    const int E = in_sizes[0] / 3;
    const int N = out_size / 288;
    float* A_a = (float*)d_out;
    float* Ov  = A_a + (size_t)N * 96;

    char* wsb = (char*)d_ws;
    unsigned short* wp = (unsigned short*)wsb;                  // 73728 B
    size_t off = 73728;
    int* counts = (int*)(wsb + off);  off += (((size_t)N*4 + 127) & ~127ull);
    int* cursor = (int*)(wsb + off);  off += (((size_t)N*4 + 127) & ~127ull);
    int* order  = (int*)(wsb + off);  off += (((size_t)E*4 + 127) & ~127ull);
    int* srcs   = (int*)(wsb + off);

    hipMemsetAsync(d_out, 0, (size_t)out_size * sizeof(float), stream);
    hipMemsetAsync(counts, 0, (size_t)N * 4, stream);

    pack_weights_k<<<(PACK_TOT + 255) / 256, 256, 0, stream>>>(w0, w1, w2, w3, wv, wp);
    hist_k<<<(E + 255) / 256, 256, 0, stream>>>(src, counts, E);
    scan_k<<<1, 1024, 0, stream>>>(counts, cursor, N);
    scatter_k<<<(E + 255) / 256, 256, 0, stream>>>(src, cursor, order, srcs, E);
    edge_kernel<<<(E + 127) / 128, 256, 0, stream>>>(r_ij, order, srcs, wp,
                                                     b0, b1, b2, A_a, Ov, E);
}

// Round 7
// 270.056 us; speedup vs baseline: 6.3819x; 1.1071x over previous
//
#include <hip/hip_runtime.h>
#include <math.h>

typedef float f32x4 __attribute__((ext_vector_type(4)));
typedef short s16x8 __attribute__((ext_vector_type(8)));

__device__ __forceinline__ unsigned short f2bf(float f) {
    unsigned u = __builtin_bit_cast(unsigned, f);
    u += 0x7fffu + ((u >> 16) & 1u);
    return (unsigned short)(u >> 16);
}

// ---------------- weight packing ----------------
// B-frag order: frag (kt,nt): lane l elem j holds W[n=16nt+(l&15)][k=32kt+8*(l>>4)+j]
#define PACK_TOT 36864

__global__ __launch_bounds__(256) void pack_weights_k(
    const float* __restrict__ w0, const float* __restrict__ w1,
    const float* __restrict__ w2, const float* __restrict__ w3,
    const float* __restrict__ wv, unsigned short* __restrict__ dst)
{
    int idx = blockIdx.x * 256 + threadIdx.x;
    if (idx >= PACK_TOT) return;
    const float* W; int inF, ntiles, off;
    if (idx < 3072)       { W = w0; inF = 8;  ntiles = 6; off = 0; }
    else if (idx < 12288) { W = w1; inF = 96; ntiles = 6; off = 3072; }
    else if (idx < 21504) { W = w2; inF = 96; ntiles = 6; off = 12288; }
    else if (idx < 30720) { W = w3; inF = 96; ntiles = 6; off = 21504; }
    else                  { W = wv; inF = 96; ntiles = 4; off = 30720; }
    int r  = idx - off;
    int fi = r >> 9;
    int wi = r & 511;
    int l = wi >> 3, j = wi & 7;
    int kt = fi / ntiles, nt = fi - kt * ntiles;
    int n = nt * 16 + (l & 15);
    int k = kt * 32 + ((l >> 4) << 3) + j;
    float v = (k < inF) ? W[n * inF + k] : 0.0f;
    dst[idx] = f2bf(v);
}

// ---------------- CSR build ----------------
__global__ __launch_bounds__(256) void hist_k(const int* __restrict__ src,
                                              int* __restrict__ counts, int E)
{
    int e = blockIdx.x * 256 + threadIdx.x;
    if (e < E) atomicAdd(&counts[src[e]], 1);
}

// multi-block scan: each block scans a 2048 chunk (within-chunk exclusive prefix);
// bsum[b] = chunk total
__global__ __launch_bounds__(256) void scan1_k(const int* __restrict__ counts,
                                               int* __restrict__ cursor,
                                               int* __restrict__ bsum, int N)
{
    __shared__ int wsum_s[4];
    int b = blockIdx.x, t = threadIdx.x, lane = t & 63, wid = t >> 6;
    int i0 = b * 2048 + t * 8;
    int v[8]; int s = 0;
    #pragma unroll
    for (int j = 0; j < 8; j++) { int i = i0 + j; v[j] = (i < N) ? counts[i] : 0; s += v[j]; }
    int inc = s;
    #pragma unroll
    for (int d = 1; d < 64; d <<= 1) { int o = __shfl_up(inc, d, 64); if (lane >= d) inc += o; }
    if (lane == 63) wsum_s[wid] = inc;
    __syncthreads();
    int wb = 0;
    for (int k = 0; k < wid; k++) wb += wsum_s[k];
    int run = wb + inc - s;
    #pragma unroll
    for (int j = 0; j < 8; j++) { int i = i0 + j; if (i < N) cursor[i] = run; run += v[j]; }
    if (t == 255) bsum[b] = wb + inc;
}

// single 64-lane block: bsum -> exclusive prefix of chunk totals
__global__ __launch_bounds__(64) void scan2_k(int* __restrict__ bsum, int nb)
{
    int lane = threadIdx.x;
    int v = (lane < nb) ? bsum[lane] : 0;
    int inc = v;
    #pragma unroll
    for (int d = 1; d < 64; d <<= 1) { int o = __shfl_up(inc, d, 64); if (lane >= d) inc += o; }
    if (lane < nb) bsum[lane] = inc - v;
}

__global__ __launch_bounds__(256) void scatter_k(const int* __restrict__ src,
                                                 const float* __restrict__ r_ij,
                                                 const int* __restrict__ bsum,
                                                 int* __restrict__ cursor,
                                                 int* __restrict__ order,
                                                 int* __restrict__ srcs,
                                                 float4* __restrict__ rsrt,
                                                 int use_rsrt, int E)
{
    int e = blockIdx.x * 256 + threadIdx.x;
    if (e < E) {
        int s = src[e];
        int p = bsum[s >> 11] + atomicAdd(&cursor[s], 1);
        if (use_rsrt) {
            rsrt[p] = make_float4(r_ij[3*e], r_ij[3*e+1], r_ij[3*e+2], __int_as_float(s));
        } else {
            order[p] = e;
            srcs[p] = s;
        }
    }
}

// ---------------- fused edge kernel (r3-proven structure) ----------------
// 4 waves x 32 sorted edges. MLP in-place in one LDS buffer (wave-private rows).
// Segment reduction with indicator-matrix MFMAs against fragment-order stashes
// of rad / vrad; one atomic per (segment, feature).
__global__ __launch_bounds__(256, 3) void edge_kernel(
    const float* __restrict__ r_ij,
    const int* __restrict__ order, const int* __restrict__ srcs,
    const float4* __restrict__ rsrt, int use_rsrt,
    const unsigned short* __restrict__ wp,
    const float* __restrict__ b0, const float* __restrict__ b1, const float* __restrict__ b2,
    float* __restrict__ A_a, float* __restrict__ Ov, int E)
{
    __shared__ unsigned short h_s[128 * 104];      // MLP buffer; cols 96..103 = enc; frag overlay late
    __shared__ unsigned short vfrag_s[16 * 512];   // vrad B-fragments
    __shared__ unsigned short rvb_s[3 * 128];      // bf16 rv, [c][row]
    __shared__ unsigned char  segid_s[128];
    __shared__ int  segnode_s[128];
    __shared__ int  src_s[128];
    __shared__ int  nseg_s;

    const int tid = threadIdx.x;
    const int w  = tid >> 6;
    const int l  = tid & 63;
    const int e0 = blockIdx.x * 128;
    const int lr = l & 15;
    const int lg = l >> 4;
    const int mbase = w * 32;

    // ---- stage per-edge scalars (coalesced float4 fast path)
    if (l < 32) {
        const int ml = mbase + l;
        const int pos = e0 + ml;
        float x = 0.f, y = 0.f, z = 0.f; int s = -1;
        if (pos < E) {
            if (use_rsrt) {
                float4 v4 = rsrt[pos];
                x = v4.x; y = v4.y; z = v4.z; s = __float_as_int(v4.w);
            } else {
                int e = order[pos];
                s = srcs[pos];
                x = r_ij[3*e]; y = r_ij[3*e+1]; z = r_ij[3*e+2];
            }
        }
        float r = sqrtf(x*x + y*y + z*z);
        float u = r * 4.0f;               // r * 8/R0, R0=2
        s16x8 ev;
        #pragma unroll
        for (int k = 0; k < 8; k++) {
            float t = fmaxf(1.0f - fabsf(u - (float)k), 0.0f);
            ev[k] = (short)f2bf((s >= 0) ? t : 0.0f);
        }
        *(s16x8*)&h_s[ml * 104 + 96] = ev;     // enc into pad cols
        float nn = 3.5f * r;
        float sc = (s >= 0) ? (3.5f * tanhf(nn) / fmaxf(nn, 1e-12f)) : 0.0f;
        rvb_s[0*128 + ml] = f2bf(x * sc);
        rvb_s[1*128 + ml] = f2bf(y * sc);
        rvb_s[2*128 + ml] = f2bf(z * sc);
        src_s[ml] = s;
    }
    __syncthreads();   // SYNC#1: src_s/enc visible

    // ---- wave 0: build segid / segnode / nseg (ballot-based prefix)
    if (w == 0) {
        int i = l;
        int sA = src_s[i];
        bool fA = (i == 0) || (sA != src_s[i - 1]);
        unsigned long long mA = __ballot(fA);
        unsigned long long maskA = (~0ull) >> (63 - i);
        int incA = (int)__popcll(mA & maskA);
        segid_s[i] = (unsigned char)(incA - 1);
        if (fA) segnode_s[incA - 1] = sA;
        int totA = (int)__popcll(mA);
        int jrow = 64 + i;
        int sB = src_s[jrow];
        bool fB = (sB != src_s[jrow - 1]);
        unsigned long long mB = __ballot(fB);
        int incB = (int)__popcll(mB & maskA);
        segid_s[jrow] = (unsigned char)(totA + incB - 1);
        if (fB) segnode_s[totA + incB - 1] = sB;
        if (i == 63) nseg_s = totA + (int)__popcll(mB);
    }

    float b0v[6], b1v[6], b2v[6];
    #pragma unroll
    for (int nt = 0; nt < 6; nt++) {
        b0v[nt] = b0[nt*16 + lr];
        b1v[nt] = b1[nt*16 + lr];
        b2v[nt] = b2[nt*16 + lr];
    }

    // ---- layer 0: h = enc @ w0.T + b0 (in place; enc in pad cols)
    {
        s16x8 A0[2];
        #pragma unroll
        for (int mf = 0; mf < 2; mf++) {
            s16x8 a = {0,0,0,0,0,0,0,0};
            if (l < 16) a = *(const s16x8*)&h_s[(mbase + mf*16 + lr) * 104 + 96];
            A0[mf] = a;
        }
        f32x4 acc[2][6];
        #pragma unroll
        for (int nt = 0; nt < 6; nt++) {
            s16x8 B = *(const s16x8*)&wp[nt * 512 + l * 8];
            f32x4 z4 = {0.f,0.f,0.f,0.f};
            acc[0][nt] = __builtin_amdgcn_mfma_f32_16x16x32_bf16(A0[0], B, z4, 0, 0, 0);
            acc[1][nt] = __builtin_amdgcn_mfma_f32_16x16x32_bf16(A0[1], B, z4, 0, 0, 0);
        }
        #pragma unroll
        for (int mf = 0; mf < 2; mf++)
        #pragma unroll
        for (int nt = 0; nt < 6; nt++)
        #pragma unroll
        for (int j = 0; j < 4; j++)
            h_s[(mbase + mf*16 + lg*4 + j) * 104 + nt*16 + lr] = f2bf(acc[mf][nt][j] + b0v[nt]);
    }

    // ---- layers 1,2: in-place leaky(h @ w.T + b)
    #pragma unroll
    for (int li = 0; li < 2; li++) {
        const int poff = 3072 + li * 9216;
        s16x8 A[2][3];
        #pragma unroll
        for (int mf = 0; mf < 2; mf++)
        #pragma unroll
        for (int kt = 0; kt < 3; kt++)
            A[mf][kt] = *(const s16x8*)&h_s[(mbase + mf*16 + lr) * 104 + kt*32 + lg*8];
        f32x4 a2[2][6] = {};
        #pragma unroll
        for (int nt = 0; nt < 6; nt++)
        #pragma unroll
        for (int kt = 0; kt < 3; kt++) {
            s16x8 B = *(const s16x8*)&wp[poff + (kt*6 + nt) * 512 + l * 8];
            a2[0][nt] = __builtin_amdgcn_mfma_f32_16x16x32_bf16(A[0][kt], B, a2[0][nt], 0, 0, 0);
            a2[1][nt] = __builtin_amdgcn_mfma_f32_16x16x32_bf16(A[1][kt], B, a2[1][nt], 0, 0, 0);
        }
        #pragma unroll
        for (int mf = 0; mf < 2; mf++)
        #pragma unroll
        for (int nt = 0; nt < 6; nt++)
        #pragma unroll
        for (int j = 0; j < 4; j++) {
            float v = a2[mf][nt][j] + ((li == 0) ? b1v[nt] : b2v[nt]);
            v = (v >= 0.f) ? v : 0.1f * v;
            h_s[(mbase + mf*16 + lg*4 + j) * 104 + nt*16 + lr] = f2bf(v);
        }
    }

    // ---- layer 3: rad = h @ w3.T (in place) + keep packed copy for frag stash
    uint2 radp[2][6];
    {
        s16x8 A[2][3];
        #pragma unroll
        for (int mf = 0; mf < 2; mf++)
        #pragma unroll
        for (int kt = 0; kt < 3; kt++)
            A[mf][kt] = *(const s16x8*)&h_s[(mbase + mf*16 + lr) * 104 + kt*32 + lg*8];
        f32x4 rad[2][6] = {};
        #pragma unroll
        for (int nt = 0; nt < 6; nt++)
        #pragma unroll
        for (int kt = 0; kt < 3; kt++) {
            s16x8 B = *(const s16x8*)&wp[21504 + (kt*6 + nt) * 512 + l * 8];
            rad[0][nt] = __builtin_amdgcn_mfma_f32_16x16x32_bf16(A[0][kt], B, rad[0][nt], 0, 0, 0);
            rad[1][nt] = __builtin_amdgcn_mfma_f32_16x16x32_bf16(A[1][kt], B, rad[1][nt], 0, 0, 0);
        }
        #pragma unroll
        for (int mf = 0; mf < 2; mf++)
        #pragma unroll
        for (int nt = 0; nt < 6; nt++) {
            unsigned short q0 = f2bf(rad[mf][nt][0]);
            unsigned short q1 = f2bf(rad[mf][nt][1]);
            unsigned short q2 = f2bf(rad[mf][nt][2]);
            unsigned short q3 = f2bf(rad[mf][nt][3]);
            radp[mf][nt].x = (unsigned)q0 | ((unsigned)q1 << 16);
            radp[mf][nt].y = (unsigned)q2 | ((unsigned)q3 << 16);
            h_s[(mbase + mf*16 + lg*4 + 0) * 104 + nt*16 + lr] = q0;
            h_s[(mbase + mf*16 + lg*4 + 1) * 104 + nt*16 + lr] = q1;
            h_s[(mbase + mf*16 + lg*4 + 2) * 104 + nt*16 + lr] = q2;
            h_s[(mbase + mf*16 + lg*4 + 3) * 104 + nt*16 + lr] = q3;
        }
    }

    // ---- vrad = rad @ wv.T  (A-frags from row-major rad; wave-private)
    f32x4 av[2][4] = {};
    {
        s16x8 Ar[2][3];
        #pragma unroll
        for (int mf = 0; mf < 2; mf++)
        #pragma unroll
        for (int kt = 0; kt < 3; kt++)
            Ar[mf][kt] = *(const s16x8*)&h_s[(mbase + mf*16 + lr) * 104 + kt*32 + lg*8];
        #pragma unroll
        for (int vt = 0; vt < 4; vt++)
        #pragma unroll
        for (int kt = 0; kt < 3; kt++) {
            s16x8 B = *(const s16x8*)&wp[30720 + (kt*4 + vt) * 512 + l * 8];
            av[0][vt] = __builtin_amdgcn_mfma_f32_16x16x32_bf16(Ar[0][kt], B, av[0][vt], 0, 0, 0);
            av[1][vt] = __builtin_amdgcn_mfma_f32_16x16x32_bf16(Ar[1][kt], B, av[1][vt], 0, 0, 0);
        }
    }

    __syncthreads();   // SYNC#2: all row-major reads of h done -> overlay allowed

    // ---- rad -> fragment-order stash (overlays h_s[0 .. 24576B))
    #pragma unroll
    for (int mf = 0; mf < 2; mf++)
    #pragma unroll
    for (int nt = 0; nt < 6; nt++)
        *(uint2*)&h_s[(w*6 + nt) * 512 + ((2*mf + (lg>>1))*16 + lr) * 8 + (lg&1)*4] = radp[mf][nt];

    // ---- vrad -> fragment-order stash (wave-private region of vfrag_s)
    #pragma unroll
    for (int mf = 0; mf < 2; mf++)
    #pragma unroll
    for (int vt = 0; vt < 4; vt++) {
        unsigned short q0 = f2bf(av[mf][vt][0]);
        unsigned short q1 = f2bf(av[mf][vt][1]);
        unsigned short q2 = f2bf(av[mf][vt][2]);
        unsigned short q3 = f2bf(av[mf][vt][3]);
        uint2 p; p.x = (unsigned)q0 | ((unsigned)q1 << 16); p.y = (unsigned)q2 | ((unsigned)q3 << 16);
        *(uint2*)&vfrag_s[(w*4 + vt) * 512 + ((2*mf + (lg>>1))*16 + lr) * 8 + (lg&1)*4] = p;
    }

    __syncthreads();   // SYNC#3: stashes + segid visible

    // ---- indicator-MFMA segment reduction
    const int nseg = nseg_s;
    if (w == 0) {
        // A_a[seg][feat] = I @ rad
        for (int st = 0; st * 16 < nseg; ++st) {
            const int target = st * 16 + lr;
            f32x4 acc[6] = {};
            #pragma unroll
            for (int kt = 0; kt < 4; kt++) {
                uint2 sid8 = *(const uint2*)&segid_s[kt*32 + 8*lg];
                s16x8 af;
                #pragma unroll
                for (int j = 0; j < 8; j++) {
                    unsigned word = (j < 4) ? sid8.x : sid8.y;
                    int sid = (word >> (8 * (j & 3))) & 255;
                    af[j] = (short)((sid == target) ? 0x3F80 : 0);
                }
                #pragma unroll
                for (int nt = 0; nt < 6; nt++) {
                    s16x8 B = *(const s16x8*)&h_s[(kt*6 + nt) * 512 + l * 8];
                    acc[nt] = __builtin_amdgcn_mfma_f32_16x16x32_bf16(af, B, acc[nt], 0, 0, 0);
                }
            }
            #pragma unroll
            for (int nt = 0; nt < 6; nt++)
            #pragma unroll
            for (int j = 0; j < 4; j++) {
                int g = st*16 + 4*lg + j;
                if (g < nseg) {
                    int node = segnode_s[g];
                    if (node >= 0)
                        unsafeAtomicAdd(&A_a[node*96 + nt*16 + lr], acc[nt][j]);
                }
            }
        }
    } else {
        // Ov[seg][v] for c = w-1: (I ∘ rv_c) @ vrad
        const int c = w - 1;
        for (int st = 0; st * 16 < nseg; ++st) {
            const int target = st * 16 + lr;
            f32x4 acc[4] = {};
            #pragma unroll
            for (int kt = 0; kt < 4; kt++) {
                uint2 sid8 = *(const uint2*)&segid_s[kt*32 + 8*lg];
                s16x8 rv8 = *(const s16x8*)&rvb_s[c*128 + kt*32 + 8*lg];
                s16x8 af;
                #pragma unroll
                for (int j = 0; j < 8; j++) {
                    unsigned word = (j < 4) ? sid8.x : sid8.y;
                    int sid = (word >> (8 * (j & 3))) & 255;
                    af[j] = (sid == target) ? rv8[j] : (short)0;
                }
                #pragma unroll
                for (int vt = 0; vt < 4; vt++) {
                    s16x8 B = *(const s16x8*)&vfrag_s[(kt*4 + vt) * 512 + l * 8];
                    acc[vt] = __builtin_amdgcn_mfma_f32_16x16x32_bf16(af, B, acc[vt], 0, 0, 0);
                }
            }
            #pragma unroll
            for (int vt = 0; vt < 4; vt++)
            #pragma unroll
            for (int j = 0; j < 4; j++) {
                int g = st*16 + 4*lg + j;
                if (g < nseg) {
                    int node = segnode_s[g];
                    if (node >= 0)
                        unsafeAtomicAdd(&Ov[node*192 + (vt*16 + lr)*3 + c], acc[vt][j]);
                }
            }
        }
    }
}

extern "C" void kernel_launch(void* const* d_in, const int* in_sizes, int n_in,
                              void* d_out, int out_size, void* d_ws, size_t ws_size,
                              hipStream_t stream)
{
    const float* r_ij = (const float*)d_in[0];
    const float* w0   = (const float*)d_in[1];
    const float* b0   = (const float*)d_in[2];
    const float* w1   = (const float*)d_in[3];
    const float* b1   = (const float*)d_in[4];
    const float* w2   = (const float*)d_in[5];
    const float* b2   = (const float*)d_in[6];
    const float* w3   = (const float*)d_in[7];
    const float* wv   = (const float*)d_in[8];
    const int*   src  = (const int*)d_in[9];
    const int E = in_sizes[0] / 3;
    const int N = out_size / 288;
    float* A_a = (float*)d_out;
    float* Ov  = A_a + (size_t)N * 96;

    char* wsb = (char*)d_ws;
    unsigned short* wp = (unsigned short*)wsb;                  // 73728 B
    size_t off = 73728;
    int* counts = (int*)(wsb + off);  off += (((size_t)N*4 + 127) & ~127ull);
    int* cursor = (int*)(wsb + off);  off += (((size_t)N*4 + 127) & ~127ull);
    int* bsum   = (int*)(wsb + off);  off += 256;
    // fast path: sorted float4 {x,y,z,src} per edge (16B). fallback: order+srcs.
    size_t need_rsrt = off + (size_t)E * 16;
    int use_rsrt = (need_rsrt <= ws_size) ? 1 : 0;
    float4* rsrt = (float4*)(wsb + off);
    int* order   = (int*)(wsb + off);
    int* srcs    = (int*)(wsb + off + (((size_t)E*4 + 127) & ~127ull));

    const int nb = (N + 2047) / 2048;

    hipMemsetAsync(d_out, 0, (size_t)out_size * sizeof(float), stream);
    hipMemsetAsync(counts, 0, (size_t)N * 4, stream);

    pack_weights_k<<<(PACK_TOT + 255) / 256, 256, 0, stream>>>(w0, w1, w2, w3, wv, wp);
    hist_k<<<(E + 255) / 256, 256, 0, stream>>>(src, counts, E);
    scan1_k<<<nb, 256, 0, stream>>>(counts, cursor, bsum, N);
    scan2_k<<<1, 64, 0, stream>>>(bsum, nb);
    scatter_k<<<(E + 255) / 256, 256, 0, stream>>>(src, r_ij, bsum, cursor,
                                                   order, srcs, rsrt, use_rsrt, E);
    edge_kernel<<<(E + 127) / 128, 256, 0, stream>>>(r_ij, order, srcs, rsrt, use_rsrt,
                                                     wp, b0, b1, b2, A_a, Ov, E);
}